// Round 4
// baseline (397.610 us; speedup 1.0000x reference)
//
#include <hip/hip_runtime.h>
#include <hip/hip_cooperative_groups.h>

namespace cg = cooperative_groups;

#define V_SZ 45
#define H_SZ 2048
#define W_SZ 128
#define D_SZ 200
#define X_SZ (H_SZ + W_SZ)   // 2176

// ws layout (floats)
#define WS_CTRL 0     // 3 ctrl logits
#define WS_SIN  16    // 128 stack_input (tanh'd), float4-aligned
#define WS_HNEW 160   // 2048 h_new (f32), float4-aligned

__device__ __forceinline__ float dot4(float4 a, float4 b) {
  return a.x * b.x + a.y * b.y + a.z * b.z + a.w * b.w;
}

__device__ __forceinline__ float wave_reduce(float v) {
#pragma unroll
  for (int o = 32; o > 0; o >>= 1) v += __shfl_down(v, o, 64);
  return v;
}

__device__ __forceinline__ void ctrl_softmax(const float* __restrict__ ws,
                                             float& c0, float& c1, float& c2) {
  const float l0 = ws[WS_CTRL + 0], l1 = ws[WS_CTRL + 1], l2 = ws[WS_CTRL + 2];
  const float m = fmaxf(l0, fmaxf(l1, l2));
  const float e0 = __expf(l0 - m), e1 = __expf(l1 - m), e2 = __expf(l2 - m);
  const float inv = 1.f / (e0 + e1 + e2);
  c0 = e0 * inv; c1 = e1 * inv; c2 = e2 * inv;
}

// ---------------------------------------------------------------------------
// Cooperative fused kernel: 1024 blocks x 256 threads, 4 blocks/CU guaranteed
// by __launch_bounds__(256,4) (VGPR<=128) => grid exactly co-resident.
// Block b owns GRU rows j0=2b, j1=2b+1.
// Phase A: all weight-streaming that does NOT depend on k1 (w_hh full,
//          w_ih chunks 0..511 vs emb row); blocks 0..130 also compute the
//          ctrl/sin row dots (k1) hidden inside the stream.
// sync
// Phase B: stack_top tail chunks (512..543) + reductions + gates -> h_new.
// sync
// Phase C: blocks 0..44 decode logits; blocks 45..144 new_stack.
// ---------------------------------------------------------------------------
__global__ __launch_bounds__(256, 4) void fused_all(
    const int* __restrict__ inp,
    const float* __restrict__ hidden,
    const float* __restrict__ stack,
    const float* __restrict__ emb,
    const float* __restrict__ ctrl_W,
    const float* __restrict__ ctrl_b,
    const float* __restrict__ sin_W,
    const float* __restrict__ sin_b,
    const float* __restrict__ w_ih,
    const float* __restrict__ w_hh,
    const float* __restrict__ b_ih,
    const float* __restrict__ b_hh,
    const float* __restrict__ dec_W,
    const float* __restrict__ dec_b,
    float* __restrict__ ws,
    float* __restrict__ out) {
  cg::grid_group grid = cg::this_grid();
  const int tid = threadIdx.x;
  const int b = blockIdx.x;              // 0..1023
  const size_t j0 = (size_t)(2 * b);
  const size_t j1 = j0 + 1;

  __shared__ float smem[4][12];
  __shared__ float sred[4];

  // 12 row pointers (float4 view)
  const float4* wi0 = (const float4*)(w_ih + j0 * X_SZ);
  const float4* wi1 = (const float4*)(w_ih + (j0 + H_SZ) * X_SZ);
  const float4* wi2 = (const float4*)(w_ih + (j0 + 2 * H_SZ) * X_SZ);
  const float4* wi3 = (const float4*)(w_ih + j1 * X_SZ);
  const float4* wi4 = (const float4*)(w_ih + (j1 + H_SZ) * X_SZ);
  const float4* wi5 = (const float4*)(w_ih + (j1 + 2 * H_SZ) * X_SZ);
  const float4* wh0 = (const float4*)(w_hh + j0 * H_SZ);
  const float4* wh1 = (const float4*)(w_hh + (j0 + H_SZ) * H_SZ);
  const float4* wh2 = (const float4*)(w_hh + (j0 + 2 * H_SZ) * H_SZ);
  const float4* wh3 = (const float4*)(w_hh + j1 * H_SZ);
  const float4* wh4 = (const float4*)(w_hh + (j1 + H_SZ) * H_SZ);
  const float4* wh5 = (const float4*)(w_hh + (j1 + 2 * H_SZ) * H_SZ);
  const float4* emb4 = (const float4*)(emb + (size_t)inp[0] * H_SZ);
  const float4* h4 = (const float4*)hidden;

  float ai0 = 0.f, ai1 = 0.f, ai2 = 0.f, ai3 = 0.f, ai4 = 0.f, ai5 = 0.f;
  float ah0 = 0.f, ah1 = 0.f, ah2 = 0.f, ah3 = 0.f, ah4 = 0.f, ah5 = 0.f;

  // ---- Phase A: k1-independent streaming ----
#pragma unroll
  for (int q = 0; q < 2; ++q) {
    const int c = tid + q * 256;
    const float4 xv = emb4[c];
    ai0 += dot4(wi0[c], xv);
    ai1 += dot4(wi1[c], xv);
    ai2 += dot4(wi2[c], xv);
    ai3 += dot4(wi3[c], xv);
    ai4 += dot4(wi4[c], xv);
    ai5 += dot4(wi5[c], xv);
  }
#pragma unroll
  for (int q = 0; q < 2; ++q) {
    const int c = tid + q * 256;
    const float4 hv = h4[c];
    ah0 += dot4(wh0[c], hv);
    ah1 += dot4(wh1[c], hv);
    ah2 += dot4(wh2[c], hv);
    ah3 += dot4(wh3[c], hv);
    ah4 += dot4(wh4[c], hv);
    ah5 += dot4(wh5[c], hv);
  }

  // k1 rows hidden inside the stream (blocks 0..130)
  if (b < 3 + W_SZ) {
    const float* row = (b < 3) ? (ctrl_W + (size_t)b * H_SZ)
                               : (sin_W + (size_t)(b - 3) * H_SZ);
    const float4* r4 = (const float4*)row;
    float acc = dot4(r4[tid], h4[tid]) + dot4(r4[tid + 256], h4[tid + 256]);
    acc = wave_reduce(acc);
    if ((tid & 63) == 0) sred[tid >> 6] = acc;
    __syncthreads();
    if (tid == 0) {
      const float total = sred[0] + sred[1] + sred[2] + sred[3];
      if (b < 3) ws[WS_CTRL + b] = total + ctrl_b[b];
      else       ws[WS_SIN + (b - 3)] = tanhf(total + sin_b[b - 3]);
    }
  }

  grid.sync();

  // ---- Phase B: stack_top tail + gates ----
  if (tid < 32) {
    float c0, c1, c2;
    ctrl_softmax(ws, c0, c1, c2);
    const int c = 512 + tid;
    const int w = 4 * tid;
    const float4 s0 = *(const float4*)(stack + w);
    const float4 s1 = *(const float4*)(stack + W_SZ + w);
    const float4 sv = *(const float4*)(ws + WS_SIN + w);
    float4 xv;
    xv.x = c2 * s0.x + c0 * sv.x + c1 * s1.x;
    xv.y = c2 * s0.y + c0 * sv.y + c1 * s1.y;
    xv.z = c2 * s0.z + c0 * sv.z + c1 * s1.z;
    xv.w = c2 * s0.w + c0 * sv.w + c1 * s1.w;
    ai0 += dot4(wi0[c], xv);
    ai1 += dot4(wi1[c], xv);
    ai2 += dot4(wi2[c], xv);
    ai3 += dot4(wi3[c], xv);
    ai4 += dot4(wi4[c], xv);
    ai5 += dot4(wi5[c], xv);
  }

  ai0 = wave_reduce(ai0); ai1 = wave_reduce(ai1); ai2 = wave_reduce(ai2);
  ai3 = wave_reduce(ai3); ai4 = wave_reduce(ai4); ai5 = wave_reduce(ai5);
  ah0 = wave_reduce(ah0); ah1 = wave_reduce(ah1); ah2 = wave_reduce(ah2);
  ah3 = wave_reduce(ah3); ah4 = wave_reduce(ah4); ah5 = wave_reduce(ah5);
  {
    const int wv = tid >> 6;
    if ((tid & 63) == 0) {
      smem[wv][0] = ai0; smem[wv][1] = ai1; smem[wv][2] = ai2;   // j0 gi
      smem[wv][3] = ah0; smem[wv][4] = ah1; smem[wv][5] = ah2;   // j0 gh
      smem[wv][6] = ai3; smem[wv][7] = ai4; smem[wv][8] = ai5;   // j1 gi
      smem[wv][9] = ah3; smem[wv][10] = ah4; smem[wv][11] = ah5; // j1 gh
    }
  }
  __syncthreads();
  if (tid < 2) {
    const int p = tid;                 // 0 -> j0, 1 -> j1
    const size_t j = j0 + p;
    float t[6];
#pragma unroll
    for (int k = 0; k < 6; ++k)
      t[k] = smem[0][p * 6 + k] + smem[1][p * 6 + k] +
             smem[2][p * 6 + k] + smem[3][p * 6 + k];
    const float gi_r = t[0] + b_ih[j];
    const float gi_z = t[1] + b_ih[j + H_SZ];
    const float gi_n = t[2] + b_ih[j + 2 * H_SZ];
    const float gh_r = t[3] + b_hh[j];
    const float gh_z = t[4] + b_hh[j + H_SZ];
    const float gh_n = t[5] + b_hh[j + 2 * H_SZ];
    const float r = 1.f / (1.f + __expf(-(gi_r + gh_r)));
    const float z = 1.f / (1.f + __expf(-(gi_z + gh_z)));
    const float n = tanhf(gi_n + r * gh_n);
    const float hn = (1.f - z) * n + z * hidden[j];
    ws[WS_HNEW + j] = hn;
    out[V_SZ + j] = hn;
  }

  grid.sync();

  // ---- Phase C: decode logits + new_stack ----
  if (b < V_SZ) {
    const float4* row = (const float4*)(dec_W + (size_t)b * H_SZ);
    const float4* hn4 = (const float4*)(ws + WS_HNEW);
    float acc = dot4(row[tid], hn4[tid]) + dot4(row[tid + 256], hn4[tid + 256]);
    acc = wave_reduce(acc);
    __syncthreads();                    // smem reuse guard
    if ((tid & 63) == 0) sred[tid >> 6] = acc;
    __syncthreads();
    if (tid == 0)
      out[b] = sred[0] + sred[1] + sred[2] + sred[3] + dec_b[b];
  } else if (b < V_SZ + (D_SZ * W_SZ) / 256) {
    const int i = (b - V_SZ) * 256 + tid;  // 0..25599
    float c0, c1, c2;
    ctrl_softmax(ws, c0, c1, c2);
    const int d = i >> 7;
    const int w = i & (W_SZ - 1);
    const float s = stack[i];
    const float up = (d == 0) ? ws[WS_SIN + w] : stack[i - W_SZ];
    const float dn = (d == D_SZ - 1) ? 0.f : stack[i + W_SZ];
    out[V_SZ + H_SZ + i] = c2 * s + c0 * up + c1 * dn;
  }
}

// ===========================================================================
// Fallback path (proven round-3 kernels) if cooperative launch is rejected.
// ===========================================================================
__global__ __launch_bounds__(256) void k1_small_gemv(
    const float* __restrict__ hidden, const float* __restrict__ ctrl_W,
    const float* __restrict__ ctrl_b, const float* __restrict__ sin_W,
    const float* __restrict__ sin_b, float* __restrict__ ws) {
  const int b = blockIdx.x;
  const int tid = threadIdx.x;
  const float* row = (b < 3) ? (ctrl_W + (size_t)b * H_SZ)
                             : (sin_W + (size_t)(b - 3) * H_SZ);
  const float4* rw4 = (const float4*)row;
  const float4* rh4 = (const float4*)hidden;
  float acc = dot4(rw4[tid], rh4[tid]) + dot4(rw4[tid + 256], rh4[tid + 256]);
  acc = wave_reduce(acc);
  __shared__ float red[4];
  if ((tid & 63) == 0) red[tid >> 6] = acc;
  __syncthreads();
  if (tid == 0) {
    float total = red[0] + red[1] + red[2] + red[3];
    if (b < 3) ws[WS_CTRL + b] = total + ctrl_b[b];
    else       ws[WS_SIN + (b - 3)] = tanhf(total + sin_b[b - 3]);
  }
}

__global__ __launch_bounds__(256) void k3_gru(
    const int* __restrict__ inp, const float* __restrict__ hidden,
    const float* __restrict__ emb, const float* __restrict__ stack,
    const float* __restrict__ w_ih, const float* __restrict__ w_hh,
    const float* __restrict__ b_ih, const float* __restrict__ b_hh,
    float* __restrict__ ws, float* __restrict__ out) {
  const int tid = threadIdx.x;
  const int j = blockIdx.x;
  float a0 = 0.f, a1 = 0.f, a2 = 0.f, a3 = 0.f, a4 = 0.f, a5 = 0.f;
  const float4* wi0 = (const float4*)(w_ih + (size_t)j * X_SZ);
  const float4* wi1 = (const float4*)(w_ih + (size_t)(j + H_SZ) * X_SZ);
  const float4* wi2 = (const float4*)(w_ih + (size_t)(j + 2 * H_SZ) * X_SZ);
  const float4* emb4 = (const float4*)(emb + (size_t)inp[0] * H_SZ);
#pragma unroll
  for (int q = 0; q < 2; ++q) {
    const int c = tid + q * 256;
    const float4 xv = emb4[c];
    a0 += dot4(wi0[c], xv); a1 += dot4(wi1[c], xv); a2 += dot4(wi2[c], xv);
  }
  if (tid < (X_SZ - H_SZ) / 4) {
    const int c = 512 + tid;
    const int w = 4 * tid;
    float c0, c1, c2;
    ctrl_softmax(ws, c0, c1, c2);
    const float4 s0 = *(const float4*)(stack + w);
    const float4 s1 = *(const float4*)(stack + W_SZ + w);
    const float4 sv = *(const float4*)(ws + WS_SIN + w);
    float4 xv;
    xv.x = c2 * s0.x + c0 * sv.x + c1 * s1.x;
    xv.y = c2 * s0.y + c0 * sv.y + c1 * s1.y;
    xv.z = c2 * s0.z + c0 * sv.z + c1 * s1.z;
    xv.w = c2 * s0.w + c0 * sv.w + c1 * s1.w;
    a0 += dot4(wi0[c], xv); a1 += dot4(wi1[c], xv); a2 += dot4(wi2[c], xv);
  }
  const float4* wh0 = (const float4*)(w_hh + (size_t)j * H_SZ);
  const float4* wh1 = (const float4*)(w_hh + (size_t)(j + H_SZ) * H_SZ);
  const float4* wh2 = (const float4*)(w_hh + (size_t)(j + 2 * H_SZ) * H_SZ);
  const float4* h4 = (const float4*)hidden;
#pragma unroll
  for (int q = 0; q < 2; ++q) {
    const int c = tid + q * 256;
    const float4 hv = h4[c];
    a3 += dot4(wh0[c], hv); a4 += dot4(wh1[c], hv); a5 += dot4(wh2[c], hv);
  }
  a0 = wave_reduce(a0); a1 = wave_reduce(a1); a2 = wave_reduce(a2);
  a3 = wave_reduce(a3); a4 = wave_reduce(a4); a5 = wave_reduce(a5);
  __shared__ float red[4][6];
  const int wv = tid >> 6;
  if ((tid & 63) == 0) {
    red[wv][0] = a0; red[wv][1] = a1; red[wv][2] = a2;
    red[wv][3] = a3; red[wv][4] = a4; red[wv][5] = a5;
  }
  __syncthreads();
  if (tid == 0) {
    float t[6];
#pragma unroll
    for (int q = 0; q < 6; ++q)
      t[q] = red[0][q] + red[1][q] + red[2][q] + red[3][q];
    const float gi_r = t[0] + b_ih[j];
    const float gi_z = t[1] + b_ih[j + H_SZ];
    const float gi_n = t[2] + b_ih[j + 2 * H_SZ];
    const float gh_r = t[3] + b_hh[j];
    const float gh_z = t[4] + b_hh[j + H_SZ];
    const float gh_n = t[5] + b_hh[j + 2 * H_SZ];
    const float r = 1.f / (1.f + __expf(-(gi_r + gh_r)));
    const float z = 1.f / (1.f + __expf(-(gi_z + gh_z)));
    const float n = tanhf(gi_n + r * gh_n);
    const float hn = (1.f - z) * n + z * hidden[j];
    ws[WS_HNEW + j] = hn;
    out[V_SZ + j] = hn;
  }
}

__global__ __launch_bounds__(256) void k4_dec_stack(
    const float* __restrict__ dec_W, const float* __restrict__ dec_b,
    const float* __restrict__ stack, float* __restrict__ ws,
    float* __restrict__ out) {
  const int tid = threadIdx.x;
  if (blockIdx.x < V_SZ) {
    const int v = blockIdx.x;
    const float4* row = (const float4*)(dec_W + (size_t)v * H_SZ);
    const float4* hn4 = (const float4*)(ws + WS_HNEW);
    float acc = dot4(row[tid], hn4[tid]) + dot4(row[tid + 256], hn4[tid + 256]);
    acc = wave_reduce(acc);
    __shared__ float red[4];
    if ((tid & 63) == 0) red[tid >> 6] = acc;
    __syncthreads();
    if (tid == 0) out[v] = red[0] + red[1] + red[2] + red[3] + dec_b[v];
  } else {
    const int i = (blockIdx.x - V_SZ) * 256 + tid;
    float c0, c1, c2;
    ctrl_softmax(ws, c0, c1, c2);
    const int d = i >> 7;
    const int w = i & (W_SZ - 1);
    const float s = stack[i];
    const float up = (d == 0) ? ws[WS_SIN + w] : stack[i - W_SZ];
    const float dn = (d == D_SZ - 1) ? 0.f : stack[i + W_SZ];
    out[V_SZ + H_SZ + i] = c2 * s + c0 * up + c1 * dn;
  }
}

extern "C" void kernel_launch(void* const* d_in, const int* in_sizes, int n_in,
                              void* d_out, int out_size, void* d_ws, size_t ws_size,
                              hipStream_t stream) {
  const int*   inp    = (const int*)d_in[0];
  const float* hidden = (const float*)d_in[1];
  const float* stack  = (const float*)d_in[2];
  const float* emb    = (const float*)d_in[3];
  const float* ctrl_W = (const float*)d_in[4];
  const float* ctrl_b = (const float*)d_in[5];
  const float* sin_W  = (const float*)d_in[6];
  const float* sin_b  = (const float*)d_in[7];
  const float* w_ih   = (const float*)d_in[8];
  const float* w_hh   = (const float*)d_in[9];
  const float* b_ih   = (const float*)d_in[10];
  const float* b_hh   = (const float*)d_in[11];
  const float* dec_W  = (const float*)d_in[12];
  const float* dec_b  = (const float*)d_in[13];
  float* out = (float*)d_out;
  float* ws = (float*)d_ws;

  void* args[] = {(void*)&inp, (void*)&hidden, (void*)&stack, (void*)&emb,
                  (void*)&ctrl_W, (void*)&ctrl_b, (void*)&sin_W, (void*)&sin_b,
                  (void*)&w_ih, (void*)&w_hh, (void*)&b_ih, (void*)&b_hh,
                  (void*)&dec_W, (void*)&dec_b, (void*)&ws, (void*)&out};
  hipError_t err = hipLaunchCooperativeKernel((const void*)fused_all,
                                              dim3(1024), dim3(256),
                                              args, 0, stream);
  if (err != hipSuccess) {
    // Fallback: proven 3-kernel path.
    k1_small_gemv<<<3 + W_SZ, 256, 0, stream>>>(hidden, ctrl_W, ctrl_b, sin_W, sin_b, ws);
    k3_gru<<<H_SZ, 256, 0, stream>>>(inp, hidden, emb, stack, w_ih, w_hh, b_ih, b_hh, ws, out);
    k4_dec_stack<<<V_SZ + (D_SZ * W_SZ) / 256, 256, 0, stream>>>(dec_W, dec_b, stack, ws, out);
  }
}

// Round 5
// 167.052 us; speedup vs baseline: 2.3802x; 2.3802x over previous
//
#include <hip/hip_runtime.h>

#define V_SZ 45
#define H_SZ 2048
#define W_SZ 128
#define D_SZ 200
#define X_SZ (H_SZ + W_SZ)   // 2176

// ws layout (float index)
#define WS_CTRL 0     // 3 ctrl logits
#define WS_SIN  16    // 128 stack_input (tanh'd), float4-aligned
#define WS_HNEW 160   // 2048 h_new (f32), float4-aligned
#define WS_FLAG 2304  // 1 int flag (byte offset 9216), zeroed via memset node

__device__ __forceinline__ float dot4(float4 a, float4 b) {
  return a.x * b.x + a.y * b.y + a.z * b.z + a.w * b.w;
}

__device__ __forceinline__ float wave_reduce(float v) {
#pragma unroll
  for (int o = 32; o > 0; o >>= 1) v += __shfl_down(v, o, 64);
  return v;
}

__device__ __forceinline__ void ctrl_softmax(const float* __restrict__ ws,
                                             float& c0, float& c1, float& c2) {
  const float l0 = ws[WS_CTRL + 0], l1 = ws[WS_CTRL + 1], l2 = ws[WS_CTRL + 2];
  const float m = fmaxf(l0, fmaxf(l1, l2));
  const float e0 = __expf(l0 - m), e1 = __expf(l1 - m), e2 = __expf(l2 - m);
  const float inv = 1.f / (e0 + e1 + e2);
  c0 = e0 * inv; c1 = e1 * inv; c2 = e2 * inv;
}

// ---------------------------------------------------------------------------
// Fused kernel: 1024 blocks x 256 threads. Block b owns GRU rows 2b, 2b+1.
// 1) blocks 0..130 compute ctrl/sin row-dots FIRST, publish via release-flag.
// 2) all blocks stream their 12 weight rows (k1-independent, ~95% of time).
// 3) acquire-spin on flag (expected already set), add stack_top tail, gates.
// Co-residency: 64 VGPR @ launch_bounds(256,4) -> 8 blocks/CU cap = 2048 >=
// 1024-block grid, so producers are always running: no deadlock possible.
// ---------------------------------------------------------------------------
__global__ __launch_bounds__(256, 4) void fused_gru(
    const int* __restrict__ inp,
    const float* __restrict__ hidden,
    const float* __restrict__ stack,
    const float* __restrict__ emb,
    const float* __restrict__ ctrl_W,
    const float* __restrict__ ctrl_b,
    const float* __restrict__ sin_W,
    const float* __restrict__ sin_b,
    const float* __restrict__ w_ih,
    const float* __restrict__ w_hh,
    const float* __restrict__ b_ih,
    const float* __restrict__ b_hh,
    float* __restrict__ ws,
    float* __restrict__ out) {
  const int tid = threadIdx.x;
  const int b = blockIdx.x;              // 0..1023
  const size_t j0 = (size_t)(2 * b);
  const size_t j1 = j0 + 1;
  int* flag = (int*)(ws + WS_FLAG);

  __shared__ float smem[4][12];
  __shared__ float sred[4];

  const float4* h4 = (const float4*)hidden;

  // ---- step 1: k1 producers (blocks 0..130) publish ctrl/sin ASAP ----
  if (b < 3 + W_SZ) {
    const float* row = (b < 3) ? (ctrl_W + (size_t)b * H_SZ)
                               : (sin_W + (size_t)(b - 3) * H_SZ);
    const float4* r4 = (const float4*)row;
    float acc = dot4(r4[tid], h4[tid]) + dot4(r4[tid + 256], h4[tid + 256]);
    acc = wave_reduce(acc);
    if ((tid & 63) == 0) sred[tid >> 6] = acc;
    __syncthreads();
    if (tid == 0) {
      const float total = sred[0] + sred[1] + sred[2] + sred[3];
      if (b < 3) ws[WS_CTRL + b] = total + ctrl_b[b];
      else       ws[WS_SIN + (b - 3)] = tanhf(total + sin_b[b - 3]);
      __hip_atomic_fetch_add(flag, 1, __ATOMIC_RELEASE,
                             __HIP_MEMORY_SCOPE_AGENT);
    }
  }

  // ---- step 2: k1-independent weight streaming ----
  const float4* wi0 = (const float4*)(w_ih + j0 * X_SZ);
  const float4* wi1 = (const float4*)(w_ih + (j0 + H_SZ) * X_SZ);
  const float4* wi2 = (const float4*)(w_ih + (j0 + 2 * H_SZ) * X_SZ);
  const float4* wi3 = (const float4*)(w_ih + j1 * X_SZ);
  const float4* wi4 = (const float4*)(w_ih + (j1 + H_SZ) * X_SZ);
  const float4* wi5 = (const float4*)(w_ih + (j1 + 2 * H_SZ) * X_SZ);
  const float4* wh0 = (const float4*)(w_hh + j0 * H_SZ);
  const float4* wh1 = (const float4*)(w_hh + (j0 + H_SZ) * H_SZ);
  const float4* wh2 = (const float4*)(w_hh + (j0 + 2 * H_SZ) * H_SZ);
  const float4* wh3 = (const float4*)(w_hh + j1 * H_SZ);
  const float4* wh4 = (const float4*)(w_hh + (j1 + H_SZ) * H_SZ);
  const float4* wh5 = (const float4*)(w_hh + (j1 + 2 * H_SZ) * H_SZ);
  const float4* emb4 = (const float4*)(emb + (size_t)inp[0] * H_SZ);

  float ai0 = 0.f, ai1 = 0.f, ai2 = 0.f, ai3 = 0.f, ai4 = 0.f, ai5 = 0.f;
  float ah0 = 0.f, ah1 = 0.f, ah2 = 0.f, ah3 = 0.f, ah4 = 0.f, ah5 = 0.f;

#pragma unroll
  for (int q = 0; q < 2; ++q) {
    const int c = tid + q * 256;
    const float4 xv = emb4[c];
    ai0 += dot4(wi0[c], xv);
    ai1 += dot4(wi1[c], xv);
    ai2 += dot4(wi2[c], xv);
    ai3 += dot4(wi3[c], xv);
    ai4 += dot4(wi4[c], xv);
    ai5 += dot4(wi5[c], xv);
  }
#pragma unroll
  for (int q = 0; q < 2; ++q) {
    const int c = tid + q * 256;
    const float4 hv = h4[c];
    ah0 += dot4(wh0[c], hv);
    ah1 += dot4(wh1[c], hv);
    ah2 += dot4(wh2[c], hv);
    ah3 += dot4(wh3[c], hv);
    ah4 += dot4(wh4[c], hv);
    ah5 += dot4(wh5[c], hv);
  }

  // ---- step 3: acquire k1 results (expected immediate), tail + gates ----
  if (tid == 0) {
    while (__hip_atomic_load(flag, __ATOMIC_ACQUIRE,
                             __HIP_MEMORY_SCOPE_AGENT) < 3 + W_SZ) {
      __builtin_amdgcn_s_sleep(2);
    }
  }
  __syncthreads();

  if (tid < 32) {
    float c0, c1, c2;
    ctrl_softmax(ws, c0, c1, c2);
    const int c = 512 + tid;               // chunks 512..543
    const int w = 4 * tid;
    const float4 s0 = *(const float4*)(stack + w);
    const float4 s1 = *(const float4*)(stack + W_SZ + w);
    const float4 sv = *(const float4*)(ws + WS_SIN + w);
    float4 xv;
    xv.x = c2 * s0.x + c0 * sv.x + c1 * s1.x;
    xv.y = c2 * s0.y + c0 * sv.y + c1 * s1.y;
    xv.z = c2 * s0.z + c0 * sv.z + c1 * s1.z;
    xv.w = c2 * s0.w + c0 * sv.w + c1 * s1.w;
    ai0 += dot4(wi0[c], xv);
    ai1 += dot4(wi1[c], xv);
    ai2 += dot4(wi2[c], xv);
    ai3 += dot4(wi3[c], xv);
    ai4 += dot4(wi4[c], xv);
    ai5 += dot4(wi5[c], xv);
  }

  ai0 = wave_reduce(ai0); ai1 = wave_reduce(ai1); ai2 = wave_reduce(ai2);
  ai3 = wave_reduce(ai3); ai4 = wave_reduce(ai4); ai5 = wave_reduce(ai5);
  ah0 = wave_reduce(ah0); ah1 = wave_reduce(ah1); ah2 = wave_reduce(ah2);
  ah3 = wave_reduce(ah3); ah4 = wave_reduce(ah4); ah5 = wave_reduce(ah5);
  {
    const int wv = tid >> 6;
    if ((tid & 63) == 0) {
      smem[wv][0] = ai0; smem[wv][1] = ai1; smem[wv][2] = ai2;   // j0 gi
      smem[wv][3] = ah0; smem[wv][4] = ah1; smem[wv][5] = ah2;   // j0 gh
      smem[wv][6] = ai3; smem[wv][7] = ai4; smem[wv][8] = ai5;   // j1 gi
      smem[wv][9] = ah3; smem[wv][10] = ah4; smem[wv][11] = ah5; // j1 gh
    }
  }
  __syncthreads();
  if (tid < 2) {
    const int p = tid;                 // 0 -> j0, 1 -> j1
    const size_t j = j0 + p;
    float t[6];
#pragma unroll
    for (int k = 0; k < 6; ++k)
      t[k] = smem[0][p * 6 + k] + smem[1][p * 6 + k] +
             smem[2][p * 6 + k] + smem[3][p * 6 + k];
    const float gi_r = t[0] + b_ih[j];
    const float gi_z = t[1] + b_ih[j + H_SZ];
    const float gi_n = t[2] + b_ih[j + 2 * H_SZ];
    const float gh_r = t[3] + b_hh[j];
    const float gh_z = t[4] + b_hh[j + H_SZ];
    const float gh_n = t[5] + b_hh[j + 2 * H_SZ];
    const float r = 1.f / (1.f + __expf(-(gi_r + gh_r)));
    const float z = 1.f / (1.f + __expf(-(gi_z + gh_z)));
    const float n = tanhf(gi_n + r * gh_n);
    const float hn = (1.f - z) * n + z * hidden[j];
    ws[WS_HNEW + j] = hn;
    out[V_SZ + j] = hn;
  }
}

// ---------------------------------------------------------------------------
// K4: blocks 0..44 decode logits from h_new; blocks 45..144 new_stack.
// (proven round-3 kernel; runs after fused_gru via stream order)
// ---------------------------------------------------------------------------
__global__ __launch_bounds__(256) void k4_dec_stack(
    const float* __restrict__ dec_W, const float* __restrict__ dec_b,
    const float* __restrict__ stack, float* __restrict__ ws,
    float* __restrict__ out) {
  const int tid = threadIdx.x;
  if (blockIdx.x < V_SZ) {
    const int v = blockIdx.x;
    const float4* row = (const float4*)(dec_W + (size_t)v * H_SZ);
    const float4* hn4 = (const float4*)(ws + WS_HNEW);
    float acc = dot4(row[tid], hn4[tid]) + dot4(row[tid + 256], hn4[tid + 256]);
    acc = wave_reduce(acc);
    __shared__ float red[4];
    if ((tid & 63) == 0) red[tid >> 6] = acc;
    __syncthreads();
    if (tid == 0) out[v] = red[0] + red[1] + red[2] + red[3] + dec_b[v];
  } else {
    const int i = (blockIdx.x - V_SZ) * 256 + tid;  // 0..25599
    float c0, c1, c2;
    ctrl_softmax(ws, c0, c1, c2);
    const int d = i >> 7;
    const int w = i & (W_SZ - 1);
    const float s = stack[i];
    const float up = (d == 0) ? ws[WS_SIN + w] : stack[i - W_SZ];
    const float dn = (d == D_SZ - 1) ? 0.f : stack[i + W_SZ];
    out[V_SZ + H_SZ + i] = c2 * s + c0 * up + c1 * dn;
  }
}

extern "C" void kernel_launch(void* const* d_in, const int* in_sizes, int n_in,
                              void* d_out, int out_size, void* d_ws, size_t ws_size,
                              hipStream_t stream) {
  const int*   inp    = (const int*)d_in[0];
  const float* hidden = (const float*)d_in[1];
  const float* stack  = (const float*)d_in[2];
  const float* emb    = (const float*)d_in[3];
  const float* ctrl_W = (const float*)d_in[4];
  const float* ctrl_b = (const float*)d_in[5];
  const float* sin_W  = (const float*)d_in[6];
  const float* sin_b  = (const float*)d_in[7];
  const float* w_ih   = (const float*)d_in[8];
  const float* w_hh   = (const float*)d_in[9];
  const float* b_ih   = (const float*)d_in[10];
  const float* b_hh   = (const float*)d_in[11];
  const float* dec_W  = (const float*)d_in[12];
  const float* dec_b  = (const float*)d_in[13];
  float* out = (float*)d_out;
  float* ws = (float*)d_ws;

  // zero the producer-consumer flag (ws is poisoned 0xAA before every launch)
  hipMemsetAsync((char*)d_ws + WS_FLAG * sizeof(float), 0, sizeof(int), stream);

  fused_gru<<<1024, 256, 0, stream>>>(inp, hidden, stack, emb, ctrl_W, ctrl_b,
                                      sin_W, sin_b, w_ih, w_hh, b_ih, b_hh,
                                      ws, out);
  k4_dec_stack<<<V_SZ + (D_SZ * W_SZ) / 256, 256, 0, stream>>>(dec_W, dec_b,
                                                               stack, ws, out);
}

// Round 6
// 155.921 us; speedup vs baseline: 2.5501x; 1.0714x over previous
//
#include <hip/hip_runtime.h>

#define V_SZ 45
#define H_SZ 2048
#define W_SZ 128
#define D_SZ 200
#define X_SZ (H_SZ + W_SZ)   // 2176
#define N_IH 6144            // w_ih rows
#define N_HH 6144            // w_hh rows
#define N_TASKS 12419        // 6144 ih + 6144 hh + 3 ctrl + 128 sin

// ws layout (float index)
#define WS_PART     0        // 12419 raw main-dot partials:
                             //   [0,6144)      gi main (cols 0..2047)
                             //   [6144,12288)  gh (complete)
                             //   [12288,12291) ctrl raw dots
                             //   [12291,12419) sin raw dots
#define WS_CTRL_RAW 12288
#define WS_SIN_RAW  12291
#define WS_HNEW     12420    // 2048 h_new (float4-aligned: 12420%4==0)

__device__ __forceinline__ float dot4(float4 a, float4 b) {
  return a.x * b.x + a.y * b.y + a.z * b.z + a.w * b.w;
}

__device__ __forceinline__ float wave_reduce(float v) {
#pragma unroll
  for (int o = 32; o > 0; o >>= 1) v += __shfl_down(v, o, 64);
  return v;
}

// ---------------------------------------------------------------------------
// A: 12419 independent row-dots of length 2048.
// Block b owns tasks 4b..4b+3; one vector per block (emb row for b<1536,
// hidden otherwise — boundaries 6144/4=1536 and 12288/4=3072 are block-exact).
// Per thread: 8 independent weight float4 loads + 2 vector float4, one pass.
// ---------------------------------------------------------------------------
__global__ __launch_bounds__(256) void kA_rowdots(
    const int* __restrict__ inp,
    const float* __restrict__ hidden,
    const float* __restrict__ emb,
    const float* __restrict__ w_ih,
    const float* __restrict__ w_hh,
    const float* __restrict__ ctrl_W,
    const float* __restrict__ sin_W,
    float* __restrict__ ws) {
  const int tid = threadIdx.x;
  const int b = blockIdx.x;
  const int t0 = 4 * b;

  const float4* v4 = (b < 1536) ? (const float4*)(emb + (size_t)inp[0] * H_SZ)
                                : (const float4*)hidden;
  const float4 va = v4[tid];
  const float4 vb = v4[tid + 256];

  const float* p0;
  const float* p1;
  const float* p2;
  const float* p3;
  {
    const int t = t0;
    // Row pointer for task t (main 2048 columns only).
    auto rowp = [&](int tt) -> const float* {
      if (tt < N_IH)        return w_ih + (size_t)tt * X_SZ;
      if (tt < 12288)       return w_hh + (size_t)(tt - N_IH) * H_SZ;
      if (tt < 12291)       return ctrl_W + (size_t)(tt - 12288) * H_SZ;
      if (tt < N_TASKS)     return sin_W + (size_t)(tt - 12291) * H_SZ;
      return w_hh;  // dummy (valid memory); write is guarded below
    };
    p0 = rowp(t);
    p1 = rowp(t + 1);
    p2 = rowp(t + 2);
    p3 = rowp(t + 3);
  }

  const float4* r0 = (const float4*)p0;
  const float4* r1 = (const float4*)p1;
  const float4* r2 = (const float4*)p2;
  const float4* r3 = (const float4*)p3;

  // 8 independent weight loads — all in flight together.
  const float4 w0a = r0[tid], w0b = r0[tid + 256];
  const float4 w1a = r1[tid], w1b = r1[tid + 256];
  const float4 w2a = r2[tid], w2b = r2[tid + 256];
  const float4 w3a = r3[tid], w3b = r3[tid + 256];

  float a0 = dot4(w0a, va) + dot4(w0b, vb);
  float a1 = dot4(w1a, va) + dot4(w1b, vb);
  float a2 = dot4(w2a, va) + dot4(w2b, vb);
  float a3 = dot4(w3a, va) + dot4(w3b, vb);

  a0 = wave_reduce(a0);
  a1 = wave_reduce(a1);
  a2 = wave_reduce(a2);
  a3 = wave_reduce(a3);

  __shared__ float red[4][4];
  const int wv = tid >> 6;
  if ((tid & 63) == 0) {
    red[wv][0] = a0; red[wv][1] = a1; red[wv][2] = a2; red[wv][3] = a3;
  }
  __syncthreads();
  if (tid < 4 && t0 + tid < N_TASKS) {
    ws[WS_PART + t0 + tid] =
        red[0][tid] + red[1][tid] + red[2][tid] + red[3][tid];
  }
}

// ---------------------------------------------------------------------------
// B: one wave per GRU unit j (2048 waves = 512 blocks).
// Each wave self-computes ctrl softmax + sin tanh + stack_top (redundant VALU,
// no cross-block ordering needed), adds the w_ih tail (cols 2048..2175)
// contribution, combines with the main partials, applies gates -> h_new.
// ---------------------------------------------------------------------------
__global__ __launch_bounds__(256) void kB_gates(
    const float* __restrict__ stack,
    const float* __restrict__ ctrl_b,
    const float* __restrict__ sin_b,
    const float* __restrict__ w_ih,
    const float* __restrict__ b_ih,
    const float* __restrict__ b_hh,
    const float* __restrict__ hidden,
    float* __restrict__ ws,
    float* __restrict__ out) {
  const int lane = threadIdx.x & 63;
  const int j = (blockIdx.x * 256 + threadIdx.x) >> 6;   // 0..2047

  // softmax coefficients (every lane, from raw dots + bias)
  const float l0 = ws[WS_CTRL_RAW + 0] + ctrl_b[0];
  const float l1 = ws[WS_CTRL_RAW + 1] + ctrl_b[1];
  const float l2 = ws[WS_CTRL_RAW + 2] + ctrl_b[2];
  const float m = fmaxf(l0, fmaxf(l1, l2));
  const float e0 = __expf(l0 - m), e1 = __expf(l1 - m), e2 = __expf(l2 - m);
  const float inv = 1.f / (e0 + e1 + e2);
  const float c0 = e0 * inv, c1 = e1 * inv, c2 = e2 * inv;

  // stack_top elements 2*lane, 2*lane+1
  const int q0 = 2 * lane, q1 = q0 + 1;
  const float sv0 = tanhf(ws[WS_SIN_RAW + q0] + sin_b[q0]);
  const float sv1 = tanhf(ws[WS_SIN_RAW + q1] + sin_b[q1]);
  const float st0 = c2 * stack[q0] + c0 * sv0 + c1 * stack[W_SZ + q0];
  const float st1 = c2 * stack[q1] + c0 * sv1 + c1 * stack[W_SZ + q1];

  // tail dots: w_ih rows j (r), j+2048 (z), j+4096 (n), columns 2048..2175
  const float* tr = w_ih + (size_t)j * X_SZ + H_SZ;
  const float* tz = w_ih + (size_t)(j + 2048) * X_SZ + H_SZ;
  const float* tn = w_ih + (size_t)(j + 4096) * X_SZ + H_SZ;
  const float2 wr = *(const float2*)(tr + q0);
  const float2 wz = *(const float2*)(tz + q0);
  const float2 wn = *(const float2*)(tn + q0);
  float dr = wr.x * st0 + wr.y * st1;
  float dz = wz.x * st0 + wz.y * st1;
  float dn = wn.x * st0 + wn.y * st1;
  dr = wave_reduce(dr);
  dz = wave_reduce(dz);
  dn = wave_reduce(dn);

  if (lane == 0) {
    const float gi_r = ws[WS_PART + j]        + dr + b_ih[j];
    const float gi_z = ws[WS_PART + 2048 + j] + dz + b_ih[j + 2048];
    const float gi_n = ws[WS_PART + 4096 + j] + dn + b_ih[j + 4096];
    const float gh_r = ws[WS_PART + N_IH + j]        + b_hh[j];
    const float gh_z = ws[WS_PART + N_IH + 2048 + j] + b_hh[j + 2048];
    const float gh_n = ws[WS_PART + N_IH + 4096 + j] + b_hh[j + 4096];
    const float r = 1.f / (1.f + __expf(-(gi_r + gh_r)));
    const float z = 1.f / (1.f + __expf(-(gi_z + gh_z)));
    const float n = tanhf(gi_n + r * gh_n);
    const float hn = (1.f - z) * n + z * hidden[j];
    ws[WS_HNEW + j] = hn;
    out[V_SZ + j] = hn;
  }
}

// ---------------------------------------------------------------------------
// C: blocks 0..44   -> decode logits = h_new @ dec_W.T + dec_b
//    blocks 45..144 -> new_stack (self-computes softmax + sin tanh)
// ---------------------------------------------------------------------------
__global__ __launch_bounds__(256) void kC_dec_stack(
    const float* __restrict__ dec_W,
    const float* __restrict__ dec_b,
    const float* __restrict__ stack,
    const float* __restrict__ ctrl_b,
    const float* __restrict__ sin_b,
    float* __restrict__ ws,
    float* __restrict__ out) {
  const int tid = threadIdx.x;
  if (blockIdx.x < V_SZ) {
    const int v = blockIdx.x;
    const float4* row = (const float4*)(dec_W + (size_t)v * H_SZ);
    const float4* hn4 = (const float4*)(ws + WS_HNEW);
    float acc = dot4(row[tid], hn4[tid]) + dot4(row[tid + 256], hn4[tid + 256]);
    acc = wave_reduce(acc);
    __shared__ float red[4];
    if ((tid & 63) == 0) red[tid >> 6] = acc;
    __syncthreads();
    if (tid == 0) out[v] = red[0] + red[1] + red[2] + red[3] + dec_b[v];
  } else {
    const int i = (blockIdx.x - V_SZ) * 256 + tid;   // 0..25599
    const float l0 = ws[WS_CTRL_RAW + 0] + ctrl_b[0];
    const float l1 = ws[WS_CTRL_RAW + 1] + ctrl_b[1];
    const float l2 = ws[WS_CTRL_RAW + 2] + ctrl_b[2];
    const float m = fmaxf(l0, fmaxf(l1, l2));
    const float e0 = __expf(l0 - m), e1 = __expf(l1 - m), e2 = __expf(l2 - m);
    const float inv = 1.f / (e0 + e1 + e2);
    const float c0 = e0 * inv, c1 = e1 * inv, c2 = e2 * inv;
    const int d = i >> 7;
    const int w = i & (W_SZ - 1);
    const float s = stack[i];
    const float up = (d == 0) ? tanhf(ws[WS_SIN_RAW + w] + sin_b[w])
                              : stack[i - W_SZ];
    const float dn = (d == D_SZ - 1) ? 0.f : stack[i + W_SZ];
    out[V_SZ + H_SZ + i] = c2 * s + c0 * up + c1 * dn;
  }
}

extern "C" void kernel_launch(void* const* d_in, const int* in_sizes, int n_in,
                              void* d_out, int out_size, void* d_ws, size_t ws_size,
                              hipStream_t stream) {
  const int*   inp    = (const int*)d_in[0];
  const float* hidden = (const float*)d_in[1];
  const float* stack  = (const float*)d_in[2];
  const float* emb    = (const float*)d_in[3];
  const float* ctrl_W = (const float*)d_in[4];
  const float* ctrl_b = (const float*)d_in[5];
  const float* sin_W  = (const float*)d_in[6];
  const float* sin_b  = (const float*)d_in[7];
  const float* w_ih   = (const float*)d_in[8];
  const float* w_hh   = (const float*)d_in[9];
  const float* b_ih   = (const float*)d_in[10];
  const float* b_hh   = (const float*)d_in[11];
  const float* dec_W  = (const float*)d_in[12];
  const float* dec_b  = (const float*)d_in[13];
  float* out = (float*)d_out;
  float* ws = (float*)d_ws;

  kA_rowdots<<<(N_TASKS + 3) / 4, 256, 0, stream>>>(
      inp, hidden, emb, w_ih, w_hh, ctrl_W, sin_W, ws);
  kB_gates<<<512, 256, 0, stream>>>(
      stack, ctrl_b, sin_b, w_ih, b_ih, b_hh, hidden, ws, out);
  kC_dec_stack<<<V_SZ + (D_SZ * W_SZ) / 256, 256, 0, stream>>>(
      dec_W, dec_b, stack, ctrl_b, sin_b, ws, out);
}